// Round 1
// baseline (81.507 us; speedup 1.0000x reference)
//
#include <hip/hip_runtime.h>

#define HH 160
#define WW 160
#define HW (HH*WW)
#define NB 16
#define NM 64
#define NC 43

constexpr float STRIDE = 4.0f;   // 640 / 160
constexpr float EPSF = 1e-7f;

struct Accums {
  double heat_sum;
  double l1_sum;
  double cls_sum;
  int num_pos_heat;
  int mask_count;
  int cls_pos;
};

// Shared geometry: must be bit-identical between k_boxes and k_cells.
__device__ __forceinline__ void box_geom(const float* __restrict__ bb,
                                         const int* __restrict__ labels, int tid,
                                         bool& valid, int& gx, int& gy,
                                         float& cx, float& cy, float& bw, float& bh) {
  float x1 = bb[tid * 4 + 0], y1 = bb[tid * 4 + 1];
  float x2 = bb[tid * 4 + 2], y2 = bb[tid * 4 + 3];
  cx = (x1 + x2) * 0.5f;
  cy = (y1 + y2) * 0.5f;
  bw = x2 - x1;
  bh = y2 - y1;
  int lab = labels[tid];
  valid = (lab >= 0) && ((x1 + y1 + x2 + y2) > 0.0f) && (bw > 0.0f) && (bh > 0.0f);
  int tgx = (int)(cx / STRIDE);           // trunc toward zero, matches astype(int32)
  int tgy = (int)(cy / STRIDE);
  gx = tgx < 0 ? 0 : (tgx > WW - 1 ? WW - 1 : tgx);
  gy = tgy < 0 ? 0 : (tgy > HH - 1 ? HH - 1 : tgy);
}

// K1: per-box params + scatter (winner = last-m-wins via atomicMax; class label union)
__global__ void k_boxes(const float* __restrict__ bboxes, const int* __restrict__ labels,
                        float4* __restrict__ params, int* __restrict__ winner,
                        unsigned long long* __restrict__ clsmask) {
  int tid = blockIdx.x * blockDim.x + threadIdx.x;
  if (tid >= NB * NM) return;
  int b = tid / NM, m = tid % NM;
  bool valid; int gx, gy; float cx, cy, bw, bh;
  box_geom(bboxes, labels, tid, valid, gx, gy, cx, cy, bw, bh);
  float rf = fmaxf(sqrtf(bw * bh) / STRIDE, 2.0f);
  float r = (float)((int)rf);             // trunc to int, back to float
  float4 p;
  p.x = (float)gx;
  p.y = (float)gy;
  p.z = valid ? 4.0f * r * r : -1.0f;     // (2r)^2 ; -1 disables invalid boxes (d>=0 > -1)
  p.w = 0.5f * r * r;                     // 2*sigma^2 = r^2/2  (exact: r^2 <= 25600)
  params[tid] = p;
  if (valid) {
    int cell = b * HW + gy * WW + gx;
    atomicMax(&winner[cell], m);
    int labc = labels[tid]; labc = labc < 0 ? 0 : (labc > NC - 1 ? NC - 1 : labc);
    atomicOr(&clsmask[cell], 1ull << labc);
  }
}

// K2: heat focal. t = max_m gauss = exp(-min_m a_m) over covered boxes.
__global__ __launch_bounds__(256) void k_heat(const float* __restrict__ pred_heat,
                                              const float4* __restrict__ params,
                                              Accums* __restrict__ acc) {
  __shared__ float4 sp[NM];
  int bimg = blockIdx.x / (HW / 256);     // 100 blocks per image -> uniform per block
  if (threadIdx.x < NM) sp[threadIdx.x] = params[bimg * NM + threadIdx.x];
  __syncthreads();

  int idx = blockIdx.x * 256 + threadIdx.x;          // global pixel index
  int pix = idx - bimg * HW;
  float xf = (float)(pix % WW);
  float yf = (float)(pix / WW);

  float mina = 3.4e38f;
  bool cover = false;
  #pragma unroll 8
  for (int m = 0; m < NM; ++m) {
    float4 p = sp[m];                      // LDS broadcast, no bank conflict
    float ddx = xf - p.x, ddy = yf - p.y;
    float d = ddx * ddx + ddy * ddy;       // exact (integers < 2^24)
    bool c = (d <= p.z);
    float a = d / p.w;                     // IEEE div, matches ref dist/(2*s^2)
    mina = c ? fminf(mina, a) : mina;
    cover |= c;
  }
  float t = cover ? expf(-mina) : 0.0f;

  float pr = pred_heat[idx];
  float p = fminf(fmaxf(pr, EPSF), 1.0f - EPSF);
  float om = 1.0f - p;
  double loss;
  int ispos;
  if (t > 0.5f) { loss = (double)(-0.25f * om * om * logf(p) * t); ispos = 1; }
  else          { loss = (double)(-0.75f * p * p * logf(om) * (1.0f - t)); ispos = 0; }

  // wave (64) reduce, then cross-wave via LDS, one atomic per block
  for (int off = 32; off > 0; off >>= 1) {
    loss += __shfl_down(loss, off);
    ispos += __shfl_down(ispos, off);
  }
  __shared__ double lred[4];
  __shared__ int npred[4];
  int wave = threadIdx.x >> 6, lane = threadIdx.x & 63;
  if (lane == 0) { lred[wave] = loss; npred[wave] = ispos; }
  __syncthreads();
  if (threadIdx.x == 0) {
    double L = lred[0] + lred[1] + lred[2] + lred[3];
    int P = npred[0] + npred[1] + npred[2] + npred[3];
    atomicAdd(&acc->heat_sum, L);
    atomicAdd(&acc->num_pos_heat, P);
  }
}

// K3: winner cells only — box L1 + class focal at gathered addresses.
__global__ void k_cells(const float* __restrict__ bboxes, const int* __restrict__ labels,
                        const float* __restrict__ pred_boxes,
                        const float* __restrict__ pred_classes,
                        const int* __restrict__ winner,
                        const unsigned long long* __restrict__ clsmask,
                        Accums* __restrict__ acc) {
  int tid = blockIdx.x * blockDim.x + threadIdx.x;
  if (tid >= NB * NM) return;
  int b = tid / NM, m = tid % NM;
  bool valid; int gx, gy; float cx, cy, bw, bh;
  box_geom(bboxes, labels, tid, valid, gx, gy, cx, cy, bw, bh);
  if (!valid) return;
  int cell = b * HW + gy * WW + gx;
  if (winner[cell] != m) return;           // exactly one owner per mask cell

  float gcx = ((float)gx + 0.5f) * STRIDE;
  float gcy = ((float)gy + 0.5f) * STRIDE;
  float dxv = (cx - gcx) / STRIDE;
  float dyv = (cy - gcy) / STRIDE;
  float dwv = logf(bw / STRIDE + 1e-6f);
  float dhv = logf(bh / STRIDE + 1e-6f);

  int off = gy * WW + gx;
  const float* pb = pred_boxes + (size_t)b * 4 * HW + off;
  float l1 = fabsf(pb[0] - dxv) + fabsf(pb[HW] - dyv) +
             fabsf(pb[2 * HW] - dwv) + fabsf(pb[3 * HW] - dhv);

  unsigned long long cm = clsmask[cell];
  const float* pc = pred_classes + (size_t)b * NC * HW + off;
  double csum = 0.0;
  for (int c = 0; c < NC; ++c) {
    float x = pc[(size_t)c * HW];
    float s = 1.0f / (1.0f + expf(-x));    // sigmoid
    float p = fminf(fmaxf(s, EPSF), 1.0f - EPSF);
    float om = 1.0f - p;
    float term = ((cm >> c) & 1ull) ? (-0.25f * om * om * logf(p))
                                    : (-0.75f * p * p * logf(om));
    csum += (double)term;
  }
  atomicAdd(&acc->l1_sum, (double)l1);
  atomicAdd(&acc->cls_sum, csum);
  atomicAdd(&acc->mask_count, 1);
  atomicAdd(&acc->cls_pos, __popcll(cm));
}

__global__ void k_final(const Accums* __restrict__ acc, float* __restrict__ out) {
  double nph = acc->num_pos_heat < 1 ? 1.0 : (double)acc->num_pos_heat;
  float heat = (float)(acc->heat_sum / nph);
  float box = 0.0f, cls = 0.0f;
  int mc = acc->mask_count;
  if (mc > 1) {                            // num_pos = max(mc,1) > 1  <=>  mc >= 2
    box = (float)(acc->l1_sum / (double)mc);
    int cp = acc->cls_pos < 1 ? 1 : acc->cls_pos;
    cls = (float)(acc->cls_sum / (double)cp);
  }
  out[0] = heat + box + cls;
}

extern "C" void kernel_launch(void* const* d_in, const int* in_sizes, int n_in,
                              void* d_out, int out_size, void* d_ws, size_t ws_size,
                              hipStream_t stream) {
  const float* pred_heat    = (const float*)d_in[0];   // (16,1,160,160)
  const float* pred_boxes   = (const float*)d_in[1];   // (16,4,160,160)
  const float* pred_classes = (const float*)d_in[2];   // (16,43,160,160)
  const float* bboxes       = (const float*)d_in[3];   // (16,64,4)
  const int*   labels       = (const int*)d_in[4];     // (16,64) int32

  char* ws = (char*)d_ws;
  // layout: [Accums pad64][clsmask u64 B*HW][params float4 B*M][winner int B*HW]
  Accums* acc = (Accums*)ws;
  unsigned long long* clsmask = (unsigned long long*)(ws + 64);
  size_t clsmask_bytes = (size_t)NB * HW * 8;
  float4* params = (float4*)(ws + 64 + clsmask_bytes);
  size_t params_bytes = (size_t)NB * NM * sizeof(float4);
  int* winner = (int*)(ws + 64 + clsmask_bytes + params_bytes);

  hipMemsetAsync(ws, 0, 64 + clsmask_bytes, stream);
  hipMemsetAsync(winner, 0xFF, (size_t)NB * HW * 4, stream);  // -1

  k_boxes<<<(NB * NM + 255) / 256, 256, 0, stream>>>(bboxes, labels, params, winner, clsmask);
  k_heat<<<NB * HW / 256, 256, 0, stream>>>(pred_heat, params, acc);
  k_cells<<<(NB * NM + 255) / 256, 256, 0, stream>>>(bboxes, labels, pred_boxes,
                                                     pred_classes, winner, clsmask, acc);
  k_final<<<1, 1, 0, stream>>>(acc, (float*)d_out);
}

// Round 2
// 29.446 us; speedup vs baseline: 2.7680x; 2.7680x over previous
//
#include <hip/hip_runtime.h>

#define HH 160
#define WW 160
#define HW (HH*WW)
#define NB 16
#define NM 64
#define NC 43

constexpr float STRIDE = 4.0f;   // 640 / 160
constexpr float EPSF = 1e-7f;
constexpr float BIGF = 3.4e38f;

// Shared geometry: must be bit-identical across kernels.
__device__ __forceinline__ void box_geom(const float* __restrict__ bb,
                                         const int* __restrict__ labels, int tid,
                                         bool& valid, int& gx, int& gy,
                                         float& cx, float& cy, float& bw, float& bh) {
  float x1 = bb[tid * 4 + 0], y1 = bb[tid * 4 + 1];
  float x2 = bb[tid * 4 + 2], y2 = bb[tid * 4 + 3];
  cx = (x1 + x2) * 0.5f;
  cy = (y1 + y2) * 0.5f;
  bw = x2 - x1;
  bh = y2 - y1;
  int lab = labels[tid];
  valid = (lab >= 0) && ((x1 + y1 + x2 + y2) > 0.0f) && (bw > 0.0f) && (bh > 0.0f);
  int tgx = (int)(cx * 0.25f);            // /4 exact; trunc matches astype(int32)
  int tgy = (int)(cy * 0.25f);
  gx = tgx < 0 ? 0 : (tgx > WW - 1 ? WW - 1 : tgx);
  gy = tgy < 0 ? 0 : (tgy > HH - 1 ? HH - 1 : tgy);
}

// K1: winner scatter only (last-m-wins == atomicMax since XLA applies updates in order)
__global__ void k_boxes(const float* __restrict__ bboxes, const int* __restrict__ labels,
                        int* __restrict__ winner) {
  int tid = blockIdx.x * blockDim.x + threadIdx.x;
  if (tid >= NB * NM) return;
  bool valid; int gx, gy; float cx, cy, bw, bh;
  box_geom(bboxes, labels, tid, valid, gx, gy, cx, cy, bw, bh);
  if (valid) atomicMax(&winner[(tid / NM) * HW + gy * WW + gx], tid % NM);
}

// K2: heat focal. t = max_m gauss = exp(-min_m d*inv_m); no atomics, per-block partials.
__global__ __launch_bounds__(128) void k_heat(const float* __restrict__ pred_heat,
                                              const float* __restrict__ bboxes,
                                              const int* __restrict__ labels,
                                              double* __restrict__ hsum,
                                              int* __restrict__ hcnt) {
  __shared__ float4 sp[NM];
  int bimg = blockIdx.x / (HW / 128);     // 200 blocks per image
  if (threadIdx.x < NM) {
    int tid = bimg * NM + threadIdx.x;
    bool valid; int gx, gy; float cx, cy, bw, bh;
    box_geom(bboxes, labels, tid, valid, gx, gy, cx, cy, bw, bh);
    float rf = fmaxf(sqrtf(bw * bh) * 0.25f, 2.0f);   // fmax(NaN,2)=2 for junk boxes
    float r = (float)(int)rf;
    float rr = r * r;                      // exact (r<=160 integer)
    float4 p;
    p.x = (float)gx;
    p.y = (float)gy;
    p.z = valid ? 4.0f * rr : -1.0f;       // coverage threshold in exact-int d domain
    p.w = 2.0f / rr;                       // 1/(2*sigma^2), reciprocal once per box
    sp[threadIdx.x] = p;
  }
  __syncthreads();

  int idx = blockIdx.x * 128 + threadIdx.x;
  int pix = idx - bimg * HW;
  float xf = (float)(pix % WW);
  float yf = (float)(pix / WW);

  float m0 = BIGF, m1 = BIGF, m2 = BIGF, m3 = BIGF;   // 4 accums: break fmin chain
  #pragma unroll
  for (int m = 0; m < NM; m += 4) {
    float4 p0 = sp[m], p1 = sp[m + 1], p2 = sp[m + 2], p3 = sp[m + 3];
    { float dx = xf - p0.x, dy = yf - p0.y; float d = fmaf(dy, dy, dx * dx);
      m0 = fminf(m0, d <= p0.z ? d * p0.w : BIGF); }
    { float dx = xf - p1.x, dy = yf - p1.y; float d = fmaf(dy, dy, dx * dx);
      m1 = fminf(m1, d <= p1.z ? d * p1.w : BIGF); }
    { float dx = xf - p2.x, dy = yf - p2.y; float d = fmaf(dy, dy, dx * dx);
      m2 = fminf(m2, d <= p2.z ? d * p2.w : BIGF); }
    { float dx = xf - p3.x, dy = yf - p3.y; float d = fmaf(dy, dy, dx * dx);
      m3 = fminf(m3, d <= p3.z ? d * p3.w : BIGF); }
  }
  float mina = fminf(fminf(m0, m1), fminf(m2, m3));
  float t = expf(-mina);                   // expf(-3.4e38) == 0 exactly -> uncovered

  float pr = pred_heat[idx];
  float p = fminf(fmaxf(pr, EPSF), 1.0f - EPSF);
  float om = 1.0f - p;
  bool pos = t > 0.5f;
  float lg = logf(pos ? p : om);           // single transcendental, branch-free
  float coef = pos ? (-0.25f * om * om * t) : (-0.75f * p * p * (1.0f - t));
  double loss = (double)(coef * lg);
  int c = pos ? 1 : 0;

  for (int off = 32; off > 0; off >>= 1) {
    loss += __shfl_down(loss, off);
    c += __shfl_down(c, off);
  }
  __shared__ double lred[2];
  __shared__ int nred[2];
  int wave = threadIdx.x >> 6;
  if ((threadIdx.x & 63) == 0) { lred[wave] = loss; nred[wave] = c; }
  __syncthreads();
  if (threadIdx.x == 0) {
    hsum[blockIdx.x] = lred[0] + lred[1];
    hcnt[blockIdx.x] = nred[0] + nred[1];
  }
}

// K3: one WAVE per box. Lanes 0..42 = classes; label-union via shfl_xor OR-reduce.
__global__ __launch_bounds__(256) void k_cells(const float* __restrict__ bboxes,
                                               const int* __restrict__ labels,
                                               const float* __restrict__ pred_boxes,
                                               const float* __restrict__ pred_classes,
                                               const int* __restrict__ winner,
                                               double* __restrict__ l1p,
                                               double* __restrict__ clsp,
                                               int* __restrict__ cntp,
                                               int* __restrict__ posp) {
  int gtid = blockIdx.x * 256 + threadIdx.x;
  int w = gtid >> 6;            // wave id = box id, 0..1023
  int lane = threadIdx.x & 63;
  int b = w >> 6;               // image
  int m = w & 63;               // this wave's box index within image

  // lane's box geometry (used for the label-union over colliding boxes)
  int lbox = b * NM + lane;
  bool valid; int gx, gy; float cx, cy, bw, bh;
  box_geom(bboxes, labels, lbox, valid, gx, gy, cx, cy, bw, bh);
  int lab = labels[lbox]; lab = lab < 0 ? 0 : (lab > NC - 1 ? NC - 1 : lab);

  // broadcast own-box values from lane m (wave-uniform m)
  int   valid_m = __shfl((int)valid, m);
  int   gx_m = __shfl(gx, m), gy_m = __shfl(gy, m);
  float cx_m = __shfl(cx, m), cy_m = __shfl(cy, m);
  float bw_m = __shfl(bw, m), bh_m = __shfl(bh, m);

  double l1 = 0.0, csum = 0.0;
  int cnt = 0, pos = 0;
  if (valid_m) {
    int celloff = gy_m * WW + gx_m;
    int win = winner[b * HW + celloff];    // uniform load, wave-level broadcast
    if (win == m) {                        // exactly one owner wave per mask cell
      bool maps = valid && (gx == gx_m) && (gy == gy_m);
      unsigned long long cm = maps ? (1ull << lab) : 0ull;
      #pragma unroll
      for (int off = 1; off < 64; off <<= 1) cm |= __shfl_xor(cm, off);

      if (lane == 0) {
        float dxv = (cx_m - ((float)gx_m + 0.5f) * STRIDE) * 0.25f;
        float dyv = (cy_m - ((float)gy_m + 0.5f) * STRIDE) * 0.25f;
        float dwv = logf(bw_m * 0.25f + 1e-6f);
        float dhv = logf(bh_m * 0.25f + 1e-6f);
        const float* pb = pred_boxes + (size_t)b * 4 * HW + celloff;
        l1 = (double)(fabsf(pb[0] - dxv) + fabsf(pb[HW] - dyv) +
                      fabsf(pb[2 * HW] - dwv) + fabsf(pb[3 * HW] - dhv));
        cnt = 1;
        pos = __popcll(cm);
      }
      if (lane < NC) {
        float x = pred_classes[(size_t)b * NC * HW + (size_t)lane * HW + celloff];
        float s = 1.0f / (1.0f + expf(-x));
        float p = fminf(fmaxf(s, EPSF), 1.0f - EPSF);
        float om = 1.0f - p;
        float term = ((cm >> lane) & 1ull) ? (-0.25f * om * om * logf(p))
                                           : (-0.75f * p * p * logf(om));
        csum = (double)term;
      }
      for (int off = 32; off > 0; off >>= 1) csum += __shfl_down(csum, off);
    }
  }
  if (lane == 0) { l1p[w] = l1; clsp[w] = csum; cntp[w] = cnt; posp[w] = pos; }
}

// K4: single-block tree reduce of all partials + finalize.
__global__ __launch_bounds__(256) void k_final(const double* __restrict__ hsum,
                                               const int* __restrict__ hcnt,
                                               const double* __restrict__ l1p,
                                               const double* __restrict__ clsp,
                                               const int* __restrict__ cntp,
                                               const int* __restrict__ posp,
                                               float* __restrict__ out) {
  int t = threadIdx.x;
  double hs = 0.0, l1 = 0.0, cs = 0.0;
  int hc = 0, mc = 0, cp = 0;
  for (int i = t; i < NB * HW / 128; i += 256) { hs += hsum[i]; hc += hcnt[i]; }
  for (int i = t; i < NB * NM; i += 256) { l1 += l1p[i]; cs += clsp[i]; mc += cntp[i]; cp += posp[i]; }
  for (int off = 32; off > 0; off >>= 1) {
    hs += __shfl_down(hs, off); l1 += __shfl_down(l1, off); cs += __shfl_down(cs, off);
    hc += __shfl_down(hc, off); mc += __shfl_down(mc, off); cp += __shfl_down(cp, off);
  }
  __shared__ double sd[3][4];
  __shared__ int si[3][4];
  int wave = t >> 6;
  if ((t & 63) == 0) {
    sd[0][wave] = hs; sd[1][wave] = l1; sd[2][wave] = cs;
    si[0][wave] = hc; si[1][wave] = mc; si[2][wave] = cp;
  }
  __syncthreads();
  if (t == 0) {
    double HS = 0, L1 = 0, CS = 0; int HC = 0, MC = 0, CP = 0;
    for (int i = 0; i < 4; ++i) {
      HS += sd[0][i]; L1 += sd[1][i]; CS += sd[2][i];
      HC += si[0][i]; MC += si[1][i]; CP += si[2][i];
    }
    double nph = HC < 1 ? 1.0 : (double)HC;
    float heat = (float)(HS / nph);
    float box = 0.0f, cls = 0.0f;
    if (MC > 1) {
      box = (float)(L1 / (double)MC);
      int c = CP < 1 ? 1 : CP;
      cls = (float)(CS / (double)c);
    }
    out[0] = heat + box + cls;
  }
}

extern "C" void kernel_launch(void* const* d_in, const int* in_sizes, int n_in,
                              void* d_out, int out_size, void* d_ws, size_t ws_size,
                              hipStream_t stream) {
  const float* pred_heat    = (const float*)d_in[0];   // (16,1,160,160)
  const float* pred_boxes   = (const float*)d_in[1];   // (16,4,160,160)
  const float* pred_classes = (const float*)d_in[2];   // (16,43,160,160)
  const float* bboxes       = (const float*)d_in[3];   // (16,64,4)
  const int*   labels       = (const int*)d_in[4];     // (16,64) int32

  char* ws = (char*)d_ws;
  int*    winner = (int*)ws;                         // 1,638,400 B
  double* hsum   = (double*)(ws + 1638400);          // 3200 * 8
  int*    hcnt   = (int*)(ws + 1664000);             // 3200 * 4
  double* l1p    = (double*)(ws + 1676800);          // 1024 * 8
  double* clsp   = (double*)(ws + 1684992);          // 1024 * 8
  int*    cntp   = (int*)(ws + 1693184);             // 1024 * 4
  int*    posp   = (int*)(ws + 1697280);             // 1024 * 4

  hipMemsetAsync(winner, 0xFF, (size_t)NB * HW * 4, stream);   // -1

  k_boxes<<<(NB * NM + 255) / 256, 256, 0, stream>>>(bboxes, labels, winner);
  k_heat<<<NB * HW / 128, 128, 0, stream>>>(pred_heat, bboxes, labels, hsum, hcnt);
  k_cells<<<NB * NM * 64 / 256, 256, 0, stream>>>(bboxes, labels, pred_boxes,
                                                  pred_classes, winner,
                                                  l1p, clsp, cntp, posp);
  k_final<<<1, 256, 0, stream>>>(hsum, hcnt, l1p, clsp, cntp, posp, (float*)d_out);
}

// Round 3
// 24.370 us; speedup vs baseline: 3.3446x; 1.2083x over previous
//
#include <hip/hip_runtime.h>

#define HH 160
#define WW 160
#define HW (HH*WW)
#define NB 16
#define NM 64
#define NC 43

constexpr float STRIDE = 4.0f;   // 640 / 160
constexpr float EPSF = 1e-7f;
constexpr float BIGF = 3.4e38f;

// Shared geometry: must be bit-identical everywhere it is evaluated.
__device__ __forceinline__ void box_geom(const float* __restrict__ bb,
                                         const int* __restrict__ labels, int tid,
                                         bool& valid, int& gx, int& gy,
                                         float& cx, float& cy, float& bw, float& bh) {
  float x1 = bb[tid * 4 + 0], y1 = bb[tid * 4 + 1];
  float x2 = bb[tid * 4 + 2], y2 = bb[tid * 4 + 3];
  cx = (x1 + x2) * 0.5f;
  cy = (y1 + y2) * 0.5f;
  bw = x2 - x1;
  bh = y2 - y1;
  int lab = labels[tid];
  valid = (lab >= 0) && ((x1 + y1 + x2 + y2) > 0.0f) && (bw > 0.0f) && (bh > 0.0f);
  int tgx = (int)(cx * 0.25f);            // /4 exact; trunc matches astype(int32)
  int tgy = (int)(cy * 0.25f);
  gx = tgx < 0 ? 0 : (tgx > WW - 1 ? WW - 1 : tgx);
  gy = tgy < 0 ? 0 : (tgy > HH - 1 ? HH - 1 : tgy);
}

// Fused: heat focal over all pixels (every block) + winner-cell losses (blocks 0..255,
// one wave per box, ownership via ballot -- no winner array, no atomics).
__global__ __launch_bounds__(256) void k_fused(const float* __restrict__ pred_heat,
                                               const float* __restrict__ pred_boxes,
                                               const float* __restrict__ pred_classes,
                                               const float* __restrict__ bboxes,
                                               const int* __restrict__ labels,
                                               double* __restrict__ hsum,
                                               int* __restrict__ hcnt,
                                               double* __restrict__ l1p,
                                               double* __restrict__ clsp,
                                               int* __restrict__ cntp,
                                               int* __restrict__ posp) {
  __shared__ float4 sp[NM];
  int bimg = blockIdx.x / (HW / 256);     // 100 blocks per image
  if (threadIdx.x < NM) {
    int tid = bimg * NM + threadIdx.x;
    bool valid; int gx, gy; float cx, cy, bw, bh;
    box_geom(bboxes, labels, tid, valid, gx, gy, cx, cy, bw, bh);
    float rf = fmaxf(sqrtf(bw * bh) * 0.25f, 2.0f);   // fmax(NaN,2)=2 for junk boxes
    float r = (float)(int)rf;
    float nanf_ = __int_as_float(0x7fc00000);
    float4 p;
    p.x = valid ? (float)gx : nanf_;       // NaN center => a=NaN => fmin skips (IEEE)
    p.y = valid ? (float)gy : nanf_;
    p.z = 2.0f / (r * r);                  // 1/(2*sigma^2); a = d*p.z, covered iff a<=8
    p.w = 0.0f;
    sp[threadIdx.x] = p;
  }
  __syncthreads();

  int idx = blockIdx.x * 256 + threadIdx.x;
  float pr = pred_heat[idx];               // issue early, hide under the loop
  int pix = idx - bimg * HW;
  float xf = (float)(pix % WW);
  float yf = (float)(pix / WW);

  // min over a_m = d*inv_m; 5 VALU/box, 4 independent chains
  float m0 = BIGF, m1 = BIGF, m2 = BIGF, m3 = BIGF;
  #pragma unroll
  for (int m = 0; m < NM; m += 4) {
    float4 p0 = sp[m], p1 = sp[m + 1], p2 = sp[m + 2], p3 = sp[m + 3];
    { float dx = xf - p0.x, dy = yf - p0.y; m0 = fminf(m0, fmaf(dy, dy, dx * dx) * p0.z); }
    { float dx = xf - p1.x, dy = yf - p1.y; m1 = fminf(m1, fmaf(dy, dy, dx * dx) * p1.z); }
    { float dx = xf - p2.x, dy = yf - p2.y; m2 = fminf(m2, fmaf(dy, dy, dx * dx) * p2.z); }
    { float dx = xf - p3.x, dy = yf - p3.y; m3 = fminf(m3, fmaf(dy, dy, dx * dx) * p3.z); }
  }
  float mina = fminf(fminf(m0, m1), fminf(m2, m3));
  float t = (mina <= 8.0f) ? expf(-mina) : 0.0f;   // coverage: d<=4r^2 <=> a<=8

  float p = fminf(fmaxf(pr, EPSF), 1.0f - EPSF);
  float om = 1.0f - p;
  bool pos = t > 0.5f;
  float lg = logf(pos ? p : om);
  float coef = pos ? (-0.25f * om * om * t) : (-0.75f * p * p * (1.0f - t));
  double loss = (double)(coef * lg);
  int c = pos ? 1 : 0;
  for (int off = 32; off > 0; off >>= 1) {
    loss += __shfl_down(loss, off);
    c += __shfl_down(c, off);
  }
  int wave = threadIdx.x >> 6, lane = threadIdx.x & 63;
  int gw = blockIdx.x * 4 + wave;
  if (lane == 0) { hsum[gw] = loss; hcnt[gw] = c; }   // per-wave partials, no 2nd sync

  // ---- cells: one wave per box, blocks 0..255 (overlaps other blocks' heat) ----
  if (blockIdx.x < 256) {
    int wv = gw;                  // 0..1023 = box id
    int b = wv >> 6, m = wv & 63;
    int lbox = b * NM + lane;     // this lane's box within image b
    bool valid; int gx, gy; float cx, cy, bw, bh;
    box_geom(bboxes, labels, lbox, valid, gx, gy, cx, cy, bw, bh);
    int lab = labels[lbox]; lab = lab < 0 ? 0 : (lab > NC - 1 ? NC - 1 : lab);

    int   valid_m = __shfl((int)valid, m);
    int   gx_m = __shfl(gx, m), gy_m = __shfl(gy, m);
    float cx_m = __shfl(cx, m), cy_m = __shfl(cy, m);
    float bw_m = __shfl(bw, m), bh_m = __shfl(bh, m);

    double l1 = 0.0, csum = 0.0;
    int cnt = 0, npos = 0;
    if (valid_m) {
      bool maps = valid && (gx == gx_m) && (gy == gy_m);
      unsigned long long mk = __ballot(maps);         // valid boxes on this cell
      if ((63 - __clzll(mk)) == m) {                  // highest m wins == atomicMax
        unsigned long long cm = maps ? (1ull << lab) : 0ull;
        #pragma unroll
        for (int o = 1; o < 64; o <<= 1) cm |= __shfl_xor(cm, o);
        int celloff = gy_m * WW + gx_m;
        if (lane == 0) {
          float dxv = (cx_m - ((float)gx_m + 0.5f) * STRIDE) * 0.25f;
          float dyv = (cy_m - ((float)gy_m + 0.5f) * STRIDE) * 0.25f;
          float dwv = logf(bw_m * 0.25f + 1e-6f);
          float dhv = logf(bh_m * 0.25f + 1e-6f);
          const float* pb = pred_boxes + (size_t)b * 4 * HW + celloff;
          l1 = (double)(fabsf(pb[0] - dxv) + fabsf(pb[HW] - dyv) +
                        fabsf(pb[2 * HW] - dwv) + fabsf(pb[3 * HW] - dhv));
          cnt = 1;
          npos = __popcll(cm);
        }
        if (lane < NC) {
          float x = pred_classes[(size_t)b * NC * HW + (size_t)lane * HW + celloff];
          float s = 1.0f / (1.0f + expf(-x));
          float pc = fminf(fmaxf(s, EPSF), 1.0f - EPSF);
          float omc = 1.0f - pc;
          float term = ((cm >> lane) & 1ull) ? (-0.25f * omc * omc * logf(pc))
                                             : (-0.75f * pc * pc * logf(omc));
          csum = (double)term;
        }
        for (int o = 32; o > 0; o >>= 1) csum += __shfl_down(csum, o);
      }
    }
    if (lane == 0) { l1p[wv] = l1; clsp[wv] = csum; cntp[wv] = cnt; posp[wv] = npos; }
  }
}

// Single-block tree reduce of all partials + finalize.
__global__ __launch_bounds__(256) void k_final(const double* __restrict__ hsum,
                                               const int* __restrict__ hcnt,
                                               const double* __restrict__ l1p,
                                               const double* __restrict__ clsp,
                                               const int* __restrict__ cntp,
                                               const int* __restrict__ posp,
                                               float* __restrict__ out) {
  int t = threadIdx.x;
  double hs = 0.0, l1 = 0.0, cs = 0.0;
  int hc = 0, mc = 0, cp = 0;
  for (int i = t; i < 6400; i += 256) { hs += hsum[i]; hc += hcnt[i]; }
  for (int i = t; i < NB * NM; i += 256) { l1 += l1p[i]; cs += clsp[i]; mc += cntp[i]; cp += posp[i]; }
  for (int off = 32; off > 0; off >>= 1) {
    hs += __shfl_down(hs, off); l1 += __shfl_down(l1, off); cs += __shfl_down(cs, off);
    hc += __shfl_down(hc, off); mc += __shfl_down(mc, off); cp += __shfl_down(cp, off);
  }
  __shared__ double sd[3][4];
  __shared__ int si[3][4];
  int wave = t >> 6;
  if ((t & 63) == 0) {
    sd[0][wave] = hs; sd[1][wave] = l1; sd[2][wave] = cs;
    si[0][wave] = hc; si[1][wave] = mc; si[2][wave] = cp;
  }
  __syncthreads();
  if (t == 0) {
    double HS = 0, L1 = 0, CS = 0; int HC = 0, MC = 0, CP = 0;
    for (int i = 0; i < 4; ++i) {
      HS += sd[0][i]; L1 += sd[1][i]; CS += sd[2][i];
      HC += si[0][i]; MC += si[1][i]; CP += si[2][i];
    }
    double nph = HC < 1 ? 1.0 : (double)HC;
    float heat = (float)(HS / nph);
    float box = 0.0f, cls = 0.0f;
    if (MC > 1) {
      box = (float)(L1 / (double)MC);
      int c = CP < 1 ? 1 : CP;
      cls = (float)(CS / (double)c);
    }
    out[0] = heat + box + cls;
  }
}

extern "C" void kernel_launch(void* const* d_in, const int* in_sizes, int n_in,
                              void* d_out, int out_size, void* d_ws, size_t ws_size,
                              hipStream_t stream) {
  const float* pred_heat    = (const float*)d_in[0];   // (16,1,160,160)
  const float* pred_boxes   = (const float*)d_in[1];   // (16,4,160,160)
  const float* pred_classes = (const float*)d_in[2];   // (16,43,160,160)
  const float* bboxes       = (const float*)d_in[3];   // (16,64,4)
  const int*   labels       = (const int*)d_in[4];     // (16,64)

  char* ws = (char*)d_ws;
  double* hsum = (double*)ws;                 // 6400*8 = 51200
  int*    hcnt = (int*)(ws + 51200);          // 6400*4 = 25600
  double* l1p  = (double*)(ws + 76800);       // 1024*8
  double* clsp = (double*)(ws + 84992);       // 1024*8
  int*    cntp = (int*)(ws + 93184);          // 1024*4
  int*    posp = (int*)(ws + 97280);          // 1024*4

  k_fused<<<NB * HW / 256, 256, 0, stream>>>(pred_heat, pred_boxes, pred_classes,
                                             bboxes, labels,
                                             hsum, hcnt, l1p, clsp, cntp, posp);
  k_final<<<1, 256, 0, stream>>>(hsum, hcnt, l1p, clsp, cntp, posp, (float*)d_out);
}

// Round 4
// 16.926 us; speedup vs baseline: 4.8154x; 1.4397x over previous
//
#include <hip/hip_runtime.h>

#define HH 160
#define WW 160
#define HW (HH*WW)
#define NB 16
#define NM 64
#define NC 43

constexpr float STRIDE = 4.0f;   // 640 / 160
constexpr float EPSF = 1e-7f;
constexpr float BIGF = 3.4e38f;

// Shared geometry: must be bit-identical everywhere it is evaluated.
__device__ __forceinline__ void box_geom(const float* __restrict__ bb,
                                         const int* __restrict__ labels, int tid,
                                         bool& valid, int& gx, int& gy,
                                         float& cx, float& cy, float& bw, float& bh) {
  float x1 = bb[tid * 4 + 0], y1 = bb[tid * 4 + 1];
  float x2 = bb[tid * 4 + 2], y2 = bb[tid * 4 + 3];
  cx = (x1 + x2) * 0.5f;
  cy = (y1 + y2) * 0.5f;
  bw = x2 - x1;
  bh = y2 - y1;
  int lab = labels[tid];
  valid = (lab >= 0) && ((x1 + y1 + x2 + y2) > 0.0f) && (bw > 0.0f) && (bh > 0.0f);
  int tgx = (int)(cx * 0.25f);            // /4 exact; trunc matches astype(int32)
  int tgy = (int)(cy * 0.25f);
  gx = tgx < 0 ? 0 : (tgx > WW - 1 ? WW - 1 : tgx);
  gy = tgy < 0 ? 0 : (tgy > HH - 1 ? HH - 1 : tgy);
}

// Fused: heat focal (all blocks, 2 px/thread, polynomial distance) +
// winner-cell losses (blocks 0..511, one wave per box, ballot ownership).
__global__ __launch_bounds__(128) void k_fused(const float* __restrict__ pred_heat,
                                               const float* __restrict__ pred_boxes,
                                               const float* __restrict__ pred_classes,
                                               const float* __restrict__ bboxes,
                                               const int* __restrict__ labels,
                                               double* __restrict__ hsum,
                                               int* __restrict__ hcnt,
                                               double* __restrict__ l1p,
                                               double* __restrict__ clsp,
                                               int* __restrict__ cntp,
                                               int* __restrict__ posp) {
  __shared__ float4 sp[NM];                // (z, -2z*gx, -2z*gy, z*(gx^2+gy^2) | NaN)
  int bimg = blockIdx.x / 100;             // 100 blocks (256 px) per image
  if (threadIdx.x < NM) {
    int tid = bimg * NM + threadIdx.x;
    bool valid; int gx, gy; float cx, cy, bw, bh;
    box_geom(bboxes, labels, tid, valid, gx, gy, cx, cy, bw, bh);
    float rf = fmaxf(sqrtf(bw * bh) * 0.25f, 2.0f);   // fmax(NaN,2)=2 for junk boxes
    float r = (float)(int)rf;
    float z = 2.0f / (r * r);              // 1/(2*sigma^2); covered iff a <= 8
    float gxf = (float)gx, gyf = (float)gy;
    float4 p;
    p.x = z;
    p.y = -2.0f * z * gxf;
    p.z = -2.0f * z * gyf;
    p.w = valid ? z * fmaf(gxf, gxf, gyf * gyf) : __int_as_float(0x7fc00000);
    sp[threadIdx.x] = p;                   // NaN K => a=NaN => v_min_f32 skips (IEEE)
  }
  __syncthreads();

  int pixbase = (blockIdx.x - bimg * 100) * 256 + threadIdx.x * 2;  // within image
  int idx = bimg * HW + pixbase;
  float2 pr = *(const float2*)(pred_heat + idx);   // coalesced, issued early
  int xi = pixbase % WW;                   // even; pair never crosses a row
  float xf0 = (float)xi;
  float yf = (float)(pixbase / WW);
  float xf1 = xf0 + 1.0f;
  float s0 = fmaf(xf0, xf0, yf * yf);
  float s1 = fmaf(xf1, xf1, yf * yf);

  // a = z*s + zcx*xf + zcy*yf + K ; 4 independent fmin chains
  float m00 = BIGF, m01 = BIGF, m10 = BIGF, m11 = BIGF;
  #pragma unroll
  for (int m = 0; m < NM; m += 2) {
    float4 c0 = sp[m], c1 = sp[m + 1];
    { float base = fmaf(c0.z, yf, c0.w);
      m00 = fminf(m00, fmaf(c0.x, s0, fmaf(c0.y, xf0, base)));
      m01 = fminf(m01, fmaf(c0.x, s1, fmaf(c0.y, xf1, base))); }
    { float base = fmaf(c1.z, yf, c1.w);
      m10 = fminf(m10, fmaf(c1.x, s0, fmaf(c1.y, xf0, base)));
      m11 = fminf(m11, fmaf(c1.x, s1, fmaf(c1.y, xf1, base))); }
  }
  float mina0 = fminf(m00, m10);
  float mina1 = fminf(m01, m11);

  double loss;
  int c;
  {
    float t0 = (mina0 <= 8.0f) ? __expf(-mina0) : 0.0f;
    float t1 = (mina1 <= 8.0f) ? __expf(-mina1) : 0.0f;
    float p0 = fminf(fmaxf(pr.x, EPSF), 1.0f - EPSF);
    float p1 = fminf(fmaxf(pr.y, EPSF), 1.0f - EPSF);
    float q0 = 1.0f - p0, q1 = 1.0f - p1;
    bool pos0 = t0 > 0.5f, pos1 = t1 > 0.5f;
    float lg0 = __logf(pos0 ? p0 : q0);
    float lg1 = __logf(pos1 ? p1 : q1);
    float cf0 = pos0 ? (-0.25f * q0 * q0 * t0) : (-0.75f * p0 * p0 * (1.0f - t0));
    float cf1 = pos1 ? (-0.25f * q1 * q1 * t1) : (-0.75f * p1 * p1 * (1.0f - t1));
    loss = (double)(cf0 * lg0) + (double)(cf1 * lg1);
    c = (pos0 ? 1 : 0) + (pos1 ? 1 : 0);
  }
  for (int off = 32; off > 0; off >>= 1) {
    loss += __shfl_down(loss, off);
    c += __shfl_down(c, off);
  }
  int wave = threadIdx.x >> 6, lane = threadIdx.x & 63;
  int gw = blockIdx.x * 2 + wave;
  if (lane == 0) { hsum[gw] = loss; hcnt[gw] = c; }  // per-wave partials

  // ---- cells: one wave per box, blocks 0..511 (overlaps other blocks' heat) ----
  if (blockIdx.x < 512) {
    int wv = gw;                  // 0..1023 = box id
    int b = wv >> 6, m = wv & 63;
    int lbox = b * NM + lane;     // this lane's box within image b
    bool valid; int gx, gy; float cx, cy, bw, bh;
    box_geom(bboxes, labels, lbox, valid, gx, gy, cx, cy, bw, bh);
    int lab = labels[lbox]; lab = lab < 0 ? 0 : (lab > NC - 1 ? NC - 1 : lab);

    int   valid_m = __shfl((int)valid, m);
    int   gx_m = __shfl(gx, m), gy_m = __shfl(gy, m);
    float cx_m = __shfl(cx, m), cy_m = __shfl(cy, m);
    float bw_m = __shfl(bw, m), bh_m = __shfl(bh, m);

    double l1 = 0.0, csum = 0.0;
    int cnt = 0, npos = 0;
    if (valid_m) {
      bool maps = valid && (gx == gx_m) && (gy == gy_m);
      unsigned long long mk = __ballot(maps);         // valid boxes on this cell
      if ((63 - __clzll(mk)) == m) {                  // highest m wins == atomicMax
        unsigned long long cm = maps ? (1ull << lab) : 0ull;
        #pragma unroll
        for (int o = 1; o < 64; o <<= 1) cm |= __shfl_xor(cm, o);
        int celloff = gy_m * WW + gx_m;
        if (lane == 0) {
          float dxv = (cx_m - ((float)gx_m + 0.5f) * STRIDE) * 0.25f;
          float dyv = (cy_m - ((float)gy_m + 0.5f) * STRIDE) * 0.25f;
          float dwv = __logf(bw_m * 0.25f + 1e-6f);
          float dhv = __logf(bh_m * 0.25f + 1e-6f);
          const float* pb = pred_boxes + (size_t)b * 4 * HW + celloff;
          l1 = (double)(fabsf(pb[0] - dxv) + fabsf(pb[HW] - dyv) +
                        fabsf(pb[2 * HW] - dwv) + fabsf(pb[3 * HW] - dhv));
          cnt = 1;
          npos = __popcll(cm);
        }
        if (lane < NC) {
          float x = pred_classes[(size_t)b * NC * HW + (size_t)lane * HW + celloff];
          float s = 1.0f / (1.0f + __expf(-x));
          float pc = fminf(fmaxf(s, EPSF), 1.0f - EPSF);
          float omc = 1.0f - pc;
          float term = ((cm >> lane) & 1ull) ? (-0.25f * omc * omc * __logf(pc))
                                             : (-0.75f * pc * pc * __logf(omc));
          csum = (double)term;
        }
        for (int o = 32; o > 0; o >>= 1) csum += __shfl_down(csum, o);
      }
    }
    if (lane == 0) { l1p[wv] = l1; clsp[wv] = csum; cntp[wv] = cnt; posp[wv] = npos; }
  }
}

// Single-block tree reduce of all partials + finalize.
__global__ __launch_bounds__(1024) void k_final(const double* __restrict__ hsum,
                                                const int* __restrict__ hcnt,
                                                const double* __restrict__ l1p,
                                                const double* __restrict__ clsp,
                                                const int* __restrict__ cntp,
                                                const int* __restrict__ posp,
                                                float* __restrict__ out) {
  int t = threadIdx.x;
  double hs = 0.0, l1 = 0.0, cs = 0.0;
  int hc = 0, mc = 0, cp = 0;
  for (int i = t; i < 3200; i += 1024) { hs += hsum[i]; hc += hcnt[i]; }
  if (t < NB * NM) { l1 = l1p[t]; cs = clsp[t]; mc = cntp[t]; cp = posp[t]; }
  for (int off = 32; off > 0; off >>= 1) {
    hs += __shfl_down(hs, off); l1 += __shfl_down(l1, off); cs += __shfl_down(cs, off);
    hc += __shfl_down(hc, off); mc += __shfl_down(mc, off); cp += __shfl_down(cp, off);
  }
  __shared__ double sd[3][16];
  __shared__ int si[3][16];
  int wave = t >> 6;
  if ((t & 63) == 0) {
    sd[0][wave] = hs; sd[1][wave] = l1; sd[2][wave] = cs;
    si[0][wave] = hc; si[1][wave] = mc; si[2][wave] = cp;
  }
  __syncthreads();
  if (t == 0) {
    double HS = 0, L1 = 0, CS = 0; int HC = 0, MC = 0, CP = 0;
    for (int i = 0; i < 16; ++i) {
      HS += sd[0][i]; L1 += sd[1][i]; CS += sd[2][i];
      HC += si[0][i]; MC += si[1][i]; CP += si[2][i];
    }
    double nph = HC < 1 ? 1.0 : (double)HC;
    float heat = (float)(HS / nph);
    float box = 0.0f, cls = 0.0f;
    if (MC > 1) {
      box = (float)(L1 / (double)MC);
      int c = CP < 1 ? 1 : CP;
      cls = (float)(CS / (double)c);
    }
    out[0] = heat + box + cls;
  }
}

extern "C" void kernel_launch(void* const* d_in, const int* in_sizes, int n_in,
                              void* d_out, int out_size, void* d_ws, size_t ws_size,
                              hipStream_t stream) {
  const float* pred_heat    = (const float*)d_in[0];   // (16,1,160,160)
  const float* pred_boxes   = (const float*)d_in[1];   // (16,4,160,160)
  const float* pred_classes = (const float*)d_in[2];   // (16,43,160,160)
  const float* bboxes       = (const float*)d_in[3];   // (16,64,4)
  const int*   labels       = (const int*)d_in[4];     // (16,64)

  char* ws = (char*)d_ws;
  double* hsum = (double*)ws;                 // 3200*8 = 25600
  int*    hcnt = (int*)(ws + 25600);          // 3200*4 = 12800
  double* l1p  = (double*)(ws + 38400);       // 1024*8
  double* clsp = (double*)(ws + 46592);       // 1024*8
  int*    cntp = (int*)(ws + 54784);          // 1024*4
  int*    posp = (int*)(ws + 58880);          // 1024*4

  k_fused<<<NB * HW / 256, 128, 0, stream>>>(pred_heat, pred_boxes, pred_classes,
                                             bboxes, labels,
                                             hsum, hcnt, l1p, clsp, cntp, posp);
  k_final<<<1, 1024, 0, stream>>>(hsum, hcnt, l1p, clsp, cntp, posp, (float*)d_out);
}